// Round 1
// baseline (1219.858 us; speedup 1.0000x reference)
//
#include <hip/hip_runtime.h>

// Problem constants
// H=W=14, L=196, B=16, T=8, BT=128, D=768, DH=64, Lw=5, U=9, m=4, C=64

__device__ __forceinline__ float gelu_exact(float x) {
    return 0.5f * x * (1.0f + erff(x * 0.70710678118654752440f));
}

// ---------------------------------------------------------------------------
// K0a: fold LN gamma into in_w (A = gamma*w), transpose ext_w and out_w
// ---------------------------------------------------------------------------
__global__ void k_prep(const float* __restrict__ in_w, const float* __restrict__ gamma,
                       const float* __restrict__ ext_w, const float* __restrict__ out_w,
                       float* __restrict__ A, float* __restrict__ extT, float* __restrict__ wT) {
    int idx = blockIdx.x * 256 + threadIdx.x;
    if (idx < 64 * 768) {
        int c = idx / 768, d = idx % 768;
        A[idx]  = in_w[idx] * gamma[d];
        wT[idx] = out_w[d * 64 + c];           // wT[c][d] = out_w[d][c]
    }
    if (idx < 81 * 64) {
        int k = idx / 64, co = idx % 64;
        extT[idx] = ext_w[co * 81 + k];        // extT[k][co]
    }
}

// ---------------------------------------------------------------------------
// K0b: Gc[c] = sum_d gamma_d * w[c][d];  Bc[c] = sum_d beta_d * w[c][d] + in_b[c]
// ---------------------------------------------------------------------------
__global__ void k_gb(const float* __restrict__ in_w, const float* __restrict__ gamma,
                     const float* __restrict__ beta, const float* __restrict__ in_b,
                     float* __restrict__ Gc, float* __restrict__ Bc) {
    int c = blockIdx.x, tid = threadIdx.x;
    float s1 = 0.f, s2 = 0.f;
    for (int d = tid; d < 768; d += 256) {
        float w = in_w[c * 768 + d];
        s1 += w * gamma[d];
        s2 += w * beta[d];
    }
    __shared__ float r1[256], r2[256];
    r1[tid] = s1; r2[tid] = s2;
    __syncthreads();
    for (int s = 128; s > 0; s >>= 1) {
        if (tid < s) { r1[tid] += r1[tid + s]; r2[tid] += r2[tid + s]; }
        __syncthreads();
    }
    if (tid == 0) { Gc[c] = r1[0]; Bc[c] = r2[0] + in_b[c]; }
}

// ---------------------------------------------------------------------------
// K1: LayerNorm + projection + channel L2-normalize.
//   out fn[bt][pos][c]  (128 x 196 x 64)
//   grid (196, 4)  block 256.  Each block: one l, 32 bt rows, all 64 c.
//   LN folded: h0 = rstd*(x @ A^T) - mu*rstd*Gc + Bc
// ---------------------------------------------------------------------------
__global__ __launch_bounds__(256) void k_lnproj(
    const float* __restrict__ x, const float* __restrict__ A,
    const float* __restrict__ Gc, const float* __restrict__ Bc,
    float* __restrict__ fn)
{
    const int l   = blockIdx.x;   // 0..195
    const int bq  = blockIdx.y;   // 0..3
    const int tid = threadIdx.x;
    __shared__ __align__(16) float xs[32][68];   // staged x chunk / later h0
    __shared__ float mu_s[32], rs_s[32], inv_s[32];

    const int cgrp = tid & 15;   // 16 groups of 4 c
    const int btg  = tid >> 4;   // 16 groups of 2 bt
    const int c0 = cgrp * 4, b0 = btg * 2;

    float acc[2][4] = {};
    float ssum = 0.f, ssq = 0.f;

    for (int kc = 0; kc < 12; ++kc) {
        // stage 32 bt x 64 d chunk (coalesced, f4)
        for (int id = tid; id < 512; id += 256) {
            int bl = id >> 4, dq = id & 15;
            float4 v = *(const float4*)&x[((size_t)(l * 128 + bq * 32 + bl)) * 768 + kc * 64 + dq * 4];
            *(float4*)&xs[bl][dq * 4] = v;
        }
        __syncthreads();
        if (tid < 32) {
            for (int dq = 0; dq < 16; ++dq) {
                float4 v = *(const float4*)&xs[tid][dq * 4];
                ssum += v.x + v.y + v.z + v.w;
                ssq  += v.x * v.x + v.y * v.y + v.z * v.z + v.w * v.w;
            }
        }
        const float* Ab = &A[kc * 64];
        for (int dq = 0; dq < 16; ++dq) {
            float4 xv0 = *(const float4*)&xs[b0][dq * 4];
            float4 xv1 = *(const float4*)&xs[b0 + 1][dq * 4];
#pragma unroll
            for (int j = 0; j < 4; ++j) {
                float4 av = *(const float4*)&Ab[(size_t)(c0 + j) * 768 + dq * 4];
                acc[0][j] += xv0.x * av.x + xv0.y * av.y + xv0.z * av.z + xv0.w * av.w;
                acc[1][j] += xv1.x * av.x + xv1.y * av.y + xv1.z * av.z + xv1.w * av.w;
            }
        }
        __syncthreads();
    }
    if (tid < 32) {
        float mu  = ssum * (1.f / 768.f);
        float var = ssq * (1.f / 768.f) - mu * mu;
        mu_s[tid] = mu;
        rs_s[tid] = rsqrtf(var + 1e-5f);
    }
    __syncthreads();
    float h0v[2][4];
#pragma unroll
    for (int i = 0; i < 2; ++i) {
        float mu = mu_s[b0 + i], rs = rs_s[b0 + i];
#pragma unroll
        for (int j = 0; j < 4; ++j) {
            float a = rs * acc[i][j] - mu * rs * Gc[c0 + j] + Bc[c0 + j];
            h0v[i][j] = a;
            xs[b0 + i][c0 + j] = a;
        }
    }
    __syncthreads();
    if (tid < 32) {
        float s = 0.f;
        for (int dq = 0; dq < 16; ++dq) {
            float4 v = *(const float4*)&xs[tid][dq * 4];
            s += v.x * v.x + v.y * v.y + v.z * v.z + v.w * v.w;
        }
        inv_s[tid] = 1.f / fmaxf(sqrtf(s), 1e-7f);
    }
    __syncthreads();
#pragma unroll
    for (int i = 0; i < 2; ++i) {
        float inv = inv_s[b0 + i];
        int bt = bq * 32 + b0 + i;
        float4 v = make_float4(h0v[i][0] * inv, h0v[i][1] * inv, h0v[i][2] * inv, h0v[i][3] * inv);
        *(float4*)&fn[((size_t)bt * 196 + l) * 64 + c0] = v;
    }
}

// ---------------------------------------------------------------------------
// K2: local correlation (9x9x5 window) fused with ext 1x1 conv + bn + gelu.
//   grid (14, 640) block 256, dynamic LDS 66736 B
//   n -> (b,t,l);  out y0[(b*5+l)][co][t][pos]
// ---------------------------------------------------------------------------
__global__ __launch_bounds__(256) void k_corr_ext(
    const float* __restrict__ fn, const float* __restrict__ extT,
    const float* __restrict__ e_scale, const float* __restrict__ e_shift,
    float* __restrict__ y0)
{
    extern __shared__ float smem[];
    float* srcT  = smem;                 // [14][68]  (c-contig, pitch 68)
    float* tgtT  = smem + 952;           // [9][22][68]
    float* corr2 = smem + 14416;         // [2][14][81]

    const int h   = blockIdx.x;
    const int n   = blockIdx.y;
    const int l   = n % 5, t = (n / 5) % 8, b = n / 40;
    const int tid = threadIdx.x;
    const int bt  = b * 8 + t;
    const int tt  = t + l - 2;
    const bool tval = (tt >= 0) && (tt < 8);
    const int bt2 = b * 8 + (tval ? tt : 0);

    // stage src row h (c-contiguous in fn -> fully coalesced)
    for (int i4 = tid; i4 < 14 * 16; i4 += 256) {
        int w = i4 >> 4, c4 = i4 & 15;
        *(float4*)&srcT[w * 68 + c4 * 4] =
            *(const float4*)&fn[((size_t)bt * 196 + h * 14 + w) * 64 + c4 * 4];
    }
    // stage tgt rows h-4..h+4, width padded to 22 (zeros at borders / invalid t)
    for (int i4 = tid; i4 < 9 * 22 * 16; i4 += 256) {
        int du = i4 / (22 * 16), r = i4 % (22 * 16);
        int xx = r >> 4, c4 = r & 15;
        int row = h + du - 4, xc = xx - 4;
        float4 v = make_float4(0.f, 0.f, 0.f, 0.f);
        if (tval && row >= 0 && row < 14 && xc >= 0 && xc < 14)
            v = *(const float4*)&fn[((size_t)bt2 * 196 + row * 14 + xc) * 64 + c4 * 4];
        *(float4*)&tgtT[(du * 22 + xx) * 68 + c4 * 4] = v;
    }
    __syncthreads();

    // phase 1: corr[w][du*9+dv] over c, split c into two halves across threads
    if (tid < 252) {
        int item = tid >> 1, ch = tid & 1;
        int w = item / 9, du = item % 9;
        float acc[9] = {};
        int row = h + du - 4;
        if (tval && row >= 0 && row < 14) {
            const float* sp = &srcT[w * 68 + ch * 32];
            const float* tp = &tgtT[du * 22 * 68 + ch * 32];
            for (int cq = 0; cq < 8; ++cq) {
                float4 s4 = *(const float4*)&sp[cq * 4];
#pragma unroll
                for (int dv = 0; dv < 9; ++dv) {
                    float4 t4 = *(const float4*)&tp[(w + dv) * 68 + cq * 4];
                    acc[dv] += s4.x * t4.x + s4.y * t4.y + s4.z * t4.z + s4.w * t4.w;
                }
            }
        }
#pragma unroll
        for (int dv = 0; dv < 9; ++dv)
            corr2[(ch * 14 + w) * 81 + du * 9 + dv] = acc[dv];
    }
    __syncthreads();

    // phase 2: ext 1x1 conv (81 -> 64) + bn + gelu
    const size_t obase = ((size_t)(b * 5 + l) * 64) * 1568 + (size_t)t * 196 + h * 14;
    for (int i = tid; i < 896; i += 256) {
        int co = i / 14, w = i % 14;
        float a = 0.f;
        const float* c0p = &corr2[w * 81];
        const float* c1p = &corr2[(14 + w) * 81];
        for (int k = 0; k < 81; ++k)
            a += (c0p[k] + c1p[k]) * extT[k * 64 + co];
        float v = gelu_exact(a * e_scale[co] + e_shift[co]);
        y0[obase + (size_t)co * 1568 + w] = v;
    }
}

// ---------------------------------------------------------------------------
// 3x3 spatial conv (depth kernel 1, pad 1 on H,W), 64 c_in chunk -> 64 c_out.
//   grid (8, NB, NZ) block 256, dynamic LDS 73728 B.
//   Input tile in LDS, 16 rows x pitch-18 (zero-padded borders, bank-friendly).
//   Thread tile: 4 c_out x 14 positions (one image row). 224/256 active.
//   bn=1: out = gelu(scale*conv + shift) at (nb,co,t,pos)
//   bn=0: partial (per-chunk) write at ((z*NB+nb),co,t,pos)   [i2 partials]
// ---------------------------------------------------------------------------
__global__ __launch_bounds__(256) void k_conv3x3(
    const float* __restrict__ in, const float* __restrict__ w,
    const float* __restrict__ scale, const float* __restrict__ shift,
    float* __restrict__ out, int CT, int bn)
{
    extern __shared__ float smem[];
    float* inp = smem;   // [64][16*18]

    const int t   = blockIdx.x;
    const int nb  = blockIdx.y;
    const int z   = blockIdx.z;
    const int tid = threadIdx.x;
    const int CIN9 = CT * 64 * 9;

    // zero full tile (borders), then fill interior
    for (int i = tid; i < (64 * 288) / 2; i += 256)
        ((float2*)inp)[i] = make_float2(0.f, 0.f);
    __syncthreads();
    const size_t ibase = ((size_t)(nb * CT + z) * 64) * 1568 + (size_t)t * 196;
    for (int i = tid; i < 64 * 196; i += 256) {
        int ci = i / 196, pos = i % 196;
        int hh = pos / 14, ww = pos % 14;
        inp[ci * 288 + (hh + 1) * 18 + (ww + 1)] = in[ibase + (size_t)ci * 1568 + pos];
    }
    __syncthreads();

    float acc[4][14] = {};
    const int cg = tid / 14, hr = tid % 14;
    const int co0 = cg * 4;
    if (tid < 224) {
        for (int ci = 0; ci < 64; ++ci) {
            float r[3][16];
#pragma unroll
            for (int kh = 0; kh < 3; ++kh)
#pragma unroll
                for (int k2 = 0; k2 < 8; ++k2)
                    *(float2*)&r[kh][k2 * 2] =
                        *(const float2*)&inp[ci * 288 + (hr + kh) * 18 + k2 * 2];
            const float* wp = &w[(size_t)(z * 64 + ci) * 9];
#pragma unroll
            for (int kh = 0; kh < 3; ++kh)
#pragma unroll
                for (int kw = 0; kw < 3; ++kw) {
                    float wv[4];
#pragma unroll
                    for (int j = 0; j < 4; ++j)
                        wv[j] = wp[(size_t)(co0 + j) * CIN9 + kh * 3 + kw];
#pragma unroll
                    for (int j = 0; j < 4; ++j)
#pragma unroll
                        for (int q = 0; q < 14; ++q)
                            acc[j][q] = fmaf(r[kh][q + kw], wv[j], acc[j][q]);
                }
        }
        if (bn) {
#pragma unroll
            for (int j = 0; j < 4; ++j) {
                int co = co0 + j;
                float sc = scale[co], sh = shift[co];
                size_t ob = (size_t)(nb * 64 + co) * 1568 + (size_t)t * 196 + hr * 14;
#pragma unroll
                for (int q = 0; q < 14; ++q)
                    out[ob + q] = gelu_exact(acc[j][q] * sc + sh);
            }
        } else {
#pragma unroll
            for (int j = 0; j < 4; ++j) {
                int co = co0 + j;
                size_t ob = ((size_t)(z * gridDim.y + nb) * 64 + co) * 1568 + (size_t)t * 196 + hr * 14;
#pragma unroll
                for (int q = 0; q < 14; ++q)
                    out[ob + q] = acc[j][q];
            }
        }
    }
}

// ---------------------------------------------------------------------------
// K_sum: sum the 5 i2 partials + bn + gelu -> y3 (16,64,8,196)
// ---------------------------------------------------------------------------
__global__ void k_sum_bn(const float* __restrict__ yp, const float* __restrict__ scale,
                         const float* __restrict__ shift, float* __restrict__ y3) {
    int idx = blockIdx.x * 256 + threadIdx.x;
    if (idx >= 16 * 64 * 8 * 196) return;
    float s = 0.f;
#pragma unroll
    for (int z = 0; z < 5; ++z) s += yp[(size_t)z * 1605632 + idx];
    int co = (idx / 1568) & 63;
    y3[idx] = gelu_exact(s * scale[co] + shift[co]);
}

// ---------------------------------------------------------------------------
// K6: output GEMM  out[l][bt][d] = sum_c y3[b][c][t][l] * wT[c][d] + out_b[d]
//   grid (196, 16) block 192.  Thread: 4 d, 8 bt accumulators.
// ---------------------------------------------------------------------------
__global__ __launch_bounds__(192) void k_out(
    const float* __restrict__ y3, const float* __restrict__ wT,
    const float* __restrict__ out_b, float* __restrict__ out)
{
    const int l   = blockIdx.x;
    const int bg  = blockIdx.y;
    const int tid = threadIdx.x;
    __shared__ __align__(16) float ysB[8][64];
    for (int i = tid; i < 512; i += 192) {
        int bl = i >> 6, c = i & 63;
        int bt = bg * 8 + bl;
        ysB[bl][c] = y3[((size_t)((bt >> 3) * 64 + c) * 8 + (bt & 7)) * 196 + l];
    }
    __syncthreads();
    const int d0 = tid * 4;
    float acc[8][4] = {};
    for (int cq = 0; cq < 16; ++cq) {
        float4 ys[8];
#pragma unroll
        for (int i = 0; i < 8; ++i) ys[i] = *(const float4*)&ysB[i][cq * 4];
#pragma unroll
        for (int cc = 0; cc < 4; ++cc) {
            float4 wv = *(const float4*)&wT[(size_t)(cq * 4 + cc) * 768 + d0];
#pragma unroll
            for (int i = 0; i < 8; ++i) {
                float yv = (cc == 0) ? ys[i].x : (cc == 1) ? ys[i].y : (cc == 2) ? ys[i].z : ys[i].w;
                acc[i][0] = fmaf(yv, wv.x, acc[i][0]);
                acc[i][1] = fmaf(yv, wv.y, acc[i][1]);
                acc[i][2] = fmaf(yv, wv.z, acc[i][2]);
                acc[i][3] = fmaf(yv, wv.w, acc[i][3]);
            }
        }
    }
    float4 ob = *(const float4*)&out_b[d0];
#pragma unroll
    for (int i = 0; i < 8; ++i) {
        float4 v = make_float4(acc[i][0] + ob.x, acc[i][1] + ob.y,
                               acc[i][2] + ob.z, acc[i][3] + ob.w);
        *(float4*)&out[((size_t)(l * 128 + bg * 8 + i)) * 768 + d0] = v;
    }
}

// ---------------------------------------------------------------------------
extern "C" void kernel_launch(void* const* d_in, const int* in_sizes, int n_in,
                              void* d_out, int out_size, void* d_ws, size_t ws_size,
                              hipStream_t stream) {
    const float* x         = (const float*)d_in[0];
    const float* ln_gamma  = (const float*)d_in[1];
    const float* ln_beta   = (const float*)d_in[2];
    const float* in_w      = (const float*)d_in[3];
    const float* in_b      = (const float*)d_in[4];
    const float* ext_w     = (const float*)d_in[5];
    const float* ext_scale = (const float*)d_in[6];
    const float* ext_shift = (const float*)d_in[7];
    const float* i0_w      = (const float*)d_in[8];
    const float* i0_scale  = (const float*)d_in[9];
    const float* i0_shift  = (const float*)d_in[10];
    const float* i1_w      = (const float*)d_in[11];
    const float* i1_scale  = (const float*)d_in[12];
    const float* i1_shift  = (const float*)d_in[13];
    const float* i2_w      = (const float*)d_in[14];
    const float* i2_scale  = (const float*)d_in[15];
    const float* i2_shift  = (const float*)d_in[16];
    const float* out_w     = (const float*)d_in[17];
    const float* out_b     = (const float*)d_in[18];

    float* ws   = (float*)d_ws;
    float* A    = ws;                 // 49152
    float* Gc   = ws + 49152;         // 64
    float* Bc   = ws + 49216;         // 64
    float* extT = ws + 49280;         // 5184
    float* wT   = ws + 54464;         // 49152
    float* fn   = ws + 103616;        // 128*196*64 = 1,605,632
    float* bufA = ws + 1709248;       // 80*64*8*196 = 6,422,528 (y0, then y2)
    float* y3   = ws + 8131776;       // 1,605,632
    float* outf = (float*)d_out;      // also scratch for y1 and i2 partials

    k_prep<<<192, 256, 0, stream>>>(in_w, ln_gamma, ext_w, out_w, A, extT, wT);
    k_gb<<<64, 256, 0, stream>>>(in_w, ln_gamma, ln_beta, in_b, Gc, Bc);
    k_lnproj<<<dim3(196, 4), 256, 0, stream>>>(x, A, Gc, Bc, fn);
    k_corr_ext<<<dim3(14, 640), 256, 66736, stream>>>(fn, extT, ext_scale, ext_shift, bufA);
    // i0: bufA -> d_out (y1)
    k_conv3x3<<<dim3(8, 80, 1), 256, 73728, stream>>>(bufA, i0_w, i0_scale, i0_shift, outf, 1, 1);
    // i1: d_out -> bufA (y2)
    k_conv3x3<<<dim3(8, 80, 1), 256, 73728, stream>>>(outf, i1_w, i1_scale, i1_shift, bufA, 1, 1);
    // i2 partials: bufA -> d_out (5 x 16 x 64 x 8 x 196)
    k_conv3x3<<<dim3(8, 16, 5), 256, 73728, stream>>>(bufA, i2_w, nullptr, nullptr, outf, 5, 0);
    k_sum_bn<<<6272, 256, 0, stream>>>(outf, i2_scale, i2_shift, y3);
    k_out<<<dim3(196, 16), 192, 0, stream>>>(y3, wT, out_b, outf);
}

// Round 2
// 925.375 us; speedup vs baseline: 1.3182x; 1.3182x over previous
//
#include <hip/hip_runtime.h>

// Problem constants
// H=W=14, L=196, B=16, T=8, BT=128, D=768, DH=64, Lw=5, U=9, m=4, C=64

__device__ __forceinline__ float gelu_exact(float x) {
    return 0.5f * x * (1.0f + erff(x * 0.70710678118654752440f));
}

// ---------------------------------------------------------------------------
// K0a: fold LN gamma into in_w (A = gamma*w), transpose ext_w and out_w
// ---------------------------------------------------------------------------
__global__ void k_prep(const float* __restrict__ in_w, const float* __restrict__ gamma,
                       const float* __restrict__ ext_w, const float* __restrict__ out_w,
                       float* __restrict__ A, float* __restrict__ extT, float* __restrict__ wT) {
    int idx = blockIdx.x * 256 + threadIdx.x;
    if (idx < 64 * 768) {
        int c = idx / 768, d = idx % 768;
        A[idx]  = in_w[idx] * gamma[d];
        wT[idx] = out_w[d * 64 + c];           // wT[c][d] = out_w[d][c]
    }
    if (idx < 81 * 64) {
        int k = idx / 64, co = idx % 64;
        extT[idx] = ext_w[co * 81 + k];        // extT[k][co]
    }
}

// ---------------------------------------------------------------------------
// K0b: Gc[c] = sum_d gamma_d * w[c][d];  Bc[c] = sum_d beta_d * w[c][d] + in_b[c]
// ---------------------------------------------------------------------------
__global__ void k_gb(const float* __restrict__ in_w, const float* __restrict__ gamma,
                     const float* __restrict__ beta, const float* __restrict__ in_b,
                     float* __restrict__ Gc, float* __restrict__ Bc) {
    int c = blockIdx.x, tid = threadIdx.x;
    float s1 = 0.f, s2 = 0.f;
    for (int d = tid; d < 768; d += 256) {
        float w = in_w[c * 768 + d];
        s1 += w * gamma[d];
        s2 += w * beta[d];
    }
    __shared__ float r1[256], r2[256];
    r1[tid] = s1; r2[tid] = s2;
    __syncthreads();
    for (int s = 128; s > 0; s >>= 1) {
        if (tid < s) { r1[tid] += r1[tid + s]; r2[tid] += r2[tid + s]; }
        __syncthreads();
    }
    if (tid == 0) { Gc[c] = r1[0]; Bc[c] = r2[0] + in_b[c]; }
}

// ---------------------------------------------------------------------------
// K1 v2: LayerNorm + projection + channel L2-normalize.
//   out fn[bt][pos][c]  (128 x 196 x 64)
//   grid (196, 2)  block 128.  Block: one l, 64 bt rows, all 64 c.
//   Both operands staged in LDS; thread tile 4bt x 8c (128 FMA / 12 b128).
//   Row-swizzled LDS pitch: addr(r,d) = r*68 + (r>>2)*4 + d  (conflict-free
//   for both 4-row and 8-row stride fragment reads).
// ---------------------------------------------------------------------------
#define XPITCH(r) ((r) * 68 + ((r) >> 2) * 4)

__global__ __launch_bounds__(128) void k_lnproj(
    const float* __restrict__ x, const float* __restrict__ A,
    const float* __restrict__ Gc, const float* __restrict__ Bc,
    float* __restrict__ fn)
{
    const int l   = blockIdx.x;   // 0..195
    const int bq  = blockIdx.y;   // 0..1
    const int tid = threadIdx.x;  // 0..127

    __shared__ __align__(16) float xs[4416];
    __shared__ __align__(16) float as[4416];
    __shared__ float redA[64][16];
    __shared__ float redB[64][16];
    __shared__ float mu_s[64], rs_s[64], inv_s[64];

    const int btg  = tid >> 3;    // 0..15
    const int cgrp = tid & 7;     // 0..7
    const int b0 = btg * 4, c0 = cgrp * 8;
    const int srow = tid >> 4;    // 0..7
    const int sdq  = tid & 15;    // 0..15

    float acc[4][8] = {};
    float ssum[8] = {}, ssq[8] = {};

#pragma unroll 1
    for (int kc = 0; kc < 12; ++kc) {
        // stage x rows (coalesced: wave covers 4 rows x 64 contiguous floats)
#pragma unroll
        for (int k = 0; k < 8; ++k) {
            int r = srow + 8 * k;
            float4 v = *(const float4*)&x[((size_t)(l * 128 + bq * 64 + r)) * 768 + kc * 64 + sdq * 4];
            *(float4*)&xs[XPITCH(r) + sdq * 4] = v;
            ssum[k] += v.x + v.y + v.z + v.w;
            ssq[k]  += v.x * v.x + v.y * v.y + v.z * v.z + v.w * v.w;
        }
        // stage A chunk
#pragma unroll
        for (int k = 0; k < 8; ++k) {
            int c = srow + 8 * k;
            float4 v = *(const float4*)&A[(size_t)c * 768 + kc * 64 + sdq * 4];
            *(float4*)&as[XPITCH(c) + sdq * 4] = v;
        }
        __syncthreads();
#pragma unroll 4
        for (int dq = 0; dq < 16; ++dq) {
            float4 xv[4], av[8];
#pragma unroll
            for (int i = 0; i < 4; ++i)
                xv[i] = *(const float4*)&xs[XPITCH(b0 + i) + dq * 4];
#pragma unroll
            for (int j = 0; j < 8; ++j)
                av[j] = *(const float4*)&as[XPITCH(c0 + j) + dq * 4];
#pragma unroll
            for (int i = 0; i < 4; ++i)
#pragma unroll
                for (int j = 0; j < 8; ++j)
                    acc[i][j] += xv[i].x * av[j].x + xv[i].y * av[j].y +
                                 xv[i].z * av[j].z + xv[i].w * av[j].w;
        }
        __syncthreads();
    }

    // per-row mean/var reduction (16 partials per row)
#pragma unroll
    for (int k = 0; k < 8; ++k) {
        redA[srow + 8 * k][sdq] = ssum[k];
        redB[srow + 8 * k][sdq] = ssq[k];
    }
    __syncthreads();
    if (tid < 64) {
        float s1 = 0.f, s2 = 0.f;
        for (int q = 0; q < 16; ++q) { s1 += redA[tid][q]; s2 += redB[tid][q]; }
        float mu  = s1 * (1.f / 768.f);
        float var = s2 * (1.f / 768.f) - mu * mu;
        mu_s[tid] = mu;
        rs_s[tid] = rsqrtf(var + 1e-5f);
    }
    __syncthreads();

    // h0 = rs*acc - mu*rs*Gc + Bc ; accumulate norm partials
    float h0v[4][8];
#pragma unroll
    for (int i = 0; i < 4; ++i) {
        float mu = mu_s[b0 + i], rs = rs_s[b0 + i];
        float ns = 0.f;
#pragma unroll
        for (int j = 0; j < 8; ++j) {
            float a = rs * acc[i][j] - mu * rs * Gc[c0 + j] + Bc[c0 + j];
            h0v[i][j] = a;
            ns += a * a;
        }
        redA[b0 + i][cgrp] = ns;
    }
    __syncthreads();
    if (tid < 64) {
        float s = 0.f;
        for (int q = 0; q < 8; ++q) s += redA[tid][q];
        inv_s[tid] = 1.f / fmaxf(sqrtf(s), 1e-7f);
    }
    __syncthreads();
#pragma unroll
    for (int i = 0; i < 4; ++i) {
        float inv = inv_s[b0 + i];
        int bt = bq * 64 + b0 + i;
        float4 v0 = make_float4(h0v[i][0] * inv, h0v[i][1] * inv, h0v[i][2] * inv, h0v[i][3] * inv);
        float4 v1 = make_float4(h0v[i][4] * inv, h0v[i][5] * inv, h0v[i][6] * inv, h0v[i][7] * inv);
        *(float4*)&fn[((size_t)bt * 196 + l) * 64 + c0] = v0;
        *(float4*)&fn[((size_t)bt * 196 + l) * 64 + c0 + 4] = v1;
    }
}

// ---------------------------------------------------------------------------
// K2 v2: local correlation (9x9x5 window) fused with ext 1x1 conv + bn + gelu.
//   grid (14, 640) block 256, dynamic LDS 62368 B
//   Phase 1 combines the two c-halves via shfl_xor and writes pre-summed
//   csum[w][84]. Phase 2: thread = (co-group of 4, w); per k: 1 broadcast
//   ds_read + 1 cached extT float4 + 4 FMA (VALU-bound).
// ---------------------------------------------------------------------------
__global__ __launch_bounds__(256) void k_corr_ext(
    const float* __restrict__ fn, const float* __restrict__ extT,
    const float* __restrict__ e_scale, const float* __restrict__ e_shift,
    float* __restrict__ y0)
{
    extern __shared__ float smem[];
    float* srcT = smem;                  // [14][68]
    float* tgtT = smem + 952;            // [9][22][68]
    float* csum = smem + 14416;          // [14][84]

    const int h   = blockIdx.x;
    const int n   = blockIdx.y;
    const int l   = n % 5, t = (n / 5) % 8, b = n / 40;
    const int tid = threadIdx.x;
    const int bt  = b * 8 + t;
    const int tt  = t + l - 2;
    const bool tval = (tt >= 0) && (tt < 8);
    const int bt2 = b * 8 + (tval ? tt : 0);

    for (int i4 = tid; i4 < 14 * 16; i4 += 256) {
        int w = i4 >> 4, c4 = i4 & 15;
        *(float4*)&srcT[w * 68 + c4 * 4] =
            *(const float4*)&fn[((size_t)bt * 196 + h * 14 + w) * 64 + c4 * 4];
    }
    for (int i4 = tid; i4 < 9 * 22 * 16; i4 += 256) {
        int du = i4 / (22 * 16), r = i4 % (22 * 16);
        int xx = r >> 4, c4 = r & 15;
        int row = h + du - 4, xc = xx - 4;
        float4 v = make_float4(0.f, 0.f, 0.f, 0.f);
        if (tval && row >= 0 && row < 14 && xc >= 0 && xc < 14)
            v = *(const float4*)&fn[((size_t)bt2 * 196 + row * 14 + xc) * 64 + c4 * 4];
        *(float4*)&tgtT[(du * 22 + xx) * 68 + c4 * 4] = v;
    }
    __syncthreads();

    // phase 1: corr over c (split into two halves across lane pairs)
    if (tid < 252) {
        int item = tid >> 1, ch = tid & 1;
        int w = item / 9, du = item % 9;
        float acc[9] = {};
        int row = h + du - 4;
        if (tval && row >= 0 && row < 14) {
            const float* sp = &srcT[w * 68 + ch * 32];
            const float* tp = &tgtT[du * 22 * 68 + ch * 32];
            for (int cq = 0; cq < 8; ++cq) {
                float4 s4 = *(const float4*)&sp[cq * 4];
#pragma unroll
                for (int dv = 0; dv < 9; ++dv) {
                    float4 t4 = *(const float4*)&tp[(w + dv) * 68 + cq * 4];
                    acc[dv] += s4.x * t4.x + s4.y * t4.y + s4.z * t4.z + s4.w * t4.w;
                }
            }
        }
#pragma unroll
        for (int dv = 0; dv < 9; ++dv)
            acc[dv] += __shfl_xor(acc[dv], 1);
        if (ch == 0) {
#pragma unroll
            for (int dv = 0; dv < 9; ++dv)
                csum[w * 84 + du * 9 + dv] = acc[dv];
        }
    }
    __syncthreads();

    // phase 2: ext 1x1 conv (81 -> 64) + bn + gelu, 4 co per thread
    if (tid < 224) {
        const int w = tid % 14, cg = tid / 14;
        const int co0 = cg * 4;
        const float* cp = &csum[w * 84];
        float a0 = 0.f, a1 = 0.f, a2 = 0.f, a3 = 0.f;
#pragma unroll 3
        for (int k = 0; k < 81; ++k) {
            float s = cp[k];
            float4 e = *(const float4*)&extT[k * 64 + co0];
            a0 = fmaf(s, e.x, a0);
            a1 = fmaf(s, e.y, a1);
            a2 = fmaf(s, e.z, a2);
            a3 = fmaf(s, e.w, a3);
        }
        const size_t obase = ((size_t)(b * 5 + l) * 64) * 1568 + (size_t)t * 196 + h * 14;
        float r[4] = {a0, a1, a2, a3};
#pragma unroll
        for (int j = 0; j < 4; ++j) {
            float v = gelu_exact(r[j] * e_scale[co0 + j] + e_shift[co0 + j]);
            y0[obase + (size_t)(co0 + j) * 1568 + w] = v;
        }
    }
}

// ---------------------------------------------------------------------------
// 3x3 spatial conv (depth kernel 1, pad 1 on H,W), 64 c_in chunk -> 64 c_out.
//   grid (8, NB, NZ) block 256, dynamic LDS 73728 B.
// ---------------------------------------------------------------------------
__global__ __launch_bounds__(256) void k_conv3x3(
    const float* __restrict__ in, const float* __restrict__ w,
    const float* __restrict__ scale, const float* __restrict__ shift,
    float* __restrict__ out, int CT, int bn)
{
    extern __shared__ float smem[];
    float* inp = smem;   // [64][16*18]

    const int t   = blockIdx.x;
    const int nb  = blockIdx.y;
    const int z   = blockIdx.z;
    const int tid = threadIdx.x;
    const int CIN9 = CT * 64 * 9;

    for (int i = tid; i < (64 * 288) / 2; i += 256)
        ((float2*)inp)[i] = make_float2(0.f, 0.f);
    __syncthreads();
    const size_t ibase = ((size_t)(nb * CT + z) * 64) * 1568 + (size_t)t * 196;
    for (int i = tid; i < 64 * 196; i += 256) {
        int ci = i / 196, pos = i % 196;
        int hh = pos / 14, ww = pos % 14;
        inp[ci * 288 + (hh + 1) * 18 + (ww + 1)] = in[ibase + (size_t)ci * 1568 + pos];
    }
    __syncthreads();

    float acc[4][14] = {};
    const int cg = tid / 14, hr = tid % 14;
    const int co0 = cg * 4;
    if (tid < 224) {
        for (int ci = 0; ci < 64; ++ci) {
            float r[3][16];
#pragma unroll
            for (int kh = 0; kh < 3; ++kh)
#pragma unroll
                for (int k2 = 0; k2 < 8; ++k2)
                    *(float2*)&r[kh][k2 * 2] =
                        *(const float2*)&inp[ci * 288 + (hr + kh) * 18 + k2 * 2];
            const float* wp = &w[(size_t)(z * 64 + ci) * 9];
#pragma unroll
            for (int kh = 0; kh < 3; ++kh)
#pragma unroll
                for (int kw = 0; kw < 3; ++kw) {
                    float wv[4];
#pragma unroll
                    for (int j = 0; j < 4; ++j)
                        wv[j] = wp[(size_t)(co0 + j) * CIN9 + kh * 3 + kw];
#pragma unroll
                    for (int j = 0; j < 4; ++j)
#pragma unroll
                        for (int q = 0; q < 14; ++q)
                            acc[j][q] = fmaf(r[kh][q + kw], wv[j], acc[j][q]);
                }
        }
        if (bn) {
#pragma unroll
            for (int j = 0; j < 4; ++j) {
                int co = co0 + j;
                float sc = scale[co], sh = shift[co];
                size_t ob = (size_t)(nb * 64 + co) * 1568 + (size_t)t * 196 + hr * 14;
#pragma unroll
                for (int q = 0; q < 14; ++q)
                    out[ob + q] = gelu_exact(acc[j][q] * sc + sh);
            }
        } else {
#pragma unroll
            for (int j = 0; j < 4; ++j) {
                int co = co0 + j;
                size_t ob = ((size_t)(z * gridDim.y + nb) * 64 + co) * 1568 + (size_t)t * 196 + hr * 14;
#pragma unroll
                for (int q = 0; q < 14; ++q)
                    out[ob + q] = acc[j][q];
            }
        }
    }
}

// ---------------------------------------------------------------------------
// K_sum: sum the 5 i2 partials + bn + gelu -> y3 (16,64,8,196)
// ---------------------------------------------------------------------------
__global__ void k_sum_bn(const float* __restrict__ yp, const float* __restrict__ scale,
                         const float* __restrict__ shift, float* __restrict__ y3) {
    int idx = blockIdx.x * 256 + threadIdx.x;
    if (idx >= 16 * 64 * 8 * 196) return;
    float s = 0.f;
#pragma unroll
    for (int z = 0; z < 5; ++z) s += yp[(size_t)z * 1605632 + idx];
    int co = (idx / 1568) & 63;
    y3[idx] = gelu_exact(s * scale[co] + shift[co]);
}

// ---------------------------------------------------------------------------
// K6: output GEMM  out[l][bt][d] = sum_c y3[b][c][t][l] * wT[c][d] + out_b[d]
// ---------------------------------------------------------------------------
__global__ __launch_bounds__(192) void k_out(
    const float* __restrict__ y3, const float* __restrict__ wT,
    const float* __restrict__ out_b, float* __restrict__ out)
{
    const int l   = blockIdx.x;
    const int bg  = blockIdx.y;
    const int tid = threadIdx.x;
    __shared__ __align__(16) float ysB[8][64];
    for (int i = tid; i < 512; i += 192) {
        int bl = i >> 6, c = i & 63;
        int bt = bg * 8 + bl;
        ysB[bl][c] = y3[((size_t)((bt >> 3) * 64 + c) * 8 + (bt & 7)) * 196 + l];
    }
    __syncthreads();
    const int d0 = tid * 4;
    float acc[8][4] = {};
    for (int cq = 0; cq < 16; ++cq) {
        float4 ys[8];
#pragma unroll
        for (int i = 0; i < 8; ++i) ys[i] = *(const float4*)&ysB[i][cq * 4];
#pragma unroll
        for (int cc = 0; cc < 4; ++cc) {
            float4 wv = *(const float4*)&wT[(size_t)(cq * 4 + cc) * 768 + d0];
#pragma unroll
            for (int i = 0; i < 8; ++i) {
                float yv = (cc == 0) ? ys[i].x : (cc == 1) ? ys[i].y : (cc == 2) ? ys[i].z : ys[i].w;
                acc[i][0] = fmaf(yv, wv.x, acc[i][0]);
                acc[i][1] = fmaf(yv, wv.y, acc[i][1]);
                acc[i][2] = fmaf(yv, wv.z, acc[i][2]);
                acc[i][3] = fmaf(yv, wv.w, acc[i][3]);
            }
        }
    }
    float4 ob = *(const float4*)&out_b[d0];
#pragma unroll
    for (int i = 0; i < 8; ++i) {
        float4 v = make_float4(acc[i][0] + ob.x, acc[i][1] + ob.y,
                               acc[i][2] + ob.z, acc[i][3] + ob.w);
        *(float4*)&out[((size_t)(l * 128 + bg * 8 + i)) * 768 + d0] = v;
    }
}

// ---------------------------------------------------------------------------
extern "C" void kernel_launch(void* const* d_in, const int* in_sizes, int n_in,
                              void* d_out, int out_size, void* d_ws, size_t ws_size,
                              hipStream_t stream) {
    const float* x         = (const float*)d_in[0];
    const float* ln_gamma  = (const float*)d_in[1];
    const float* ln_beta   = (const float*)d_in[2];
    const float* in_w      = (const float*)d_in[3];
    const float* in_b      = (const float*)d_in[4];
    const float* ext_w     = (const float*)d_in[5];
    const float* ext_scale = (const float*)d_in[6];
    const float* ext_shift = (const float*)d_in[7];
    const float* i0_w      = (const float*)d_in[8];
    const float* i0_scale  = (const float*)d_in[9];
    const float* i0_shift  = (const float*)d_in[10];
    const float* i1_w      = (const float*)d_in[11];
    const float* i1_scale  = (const float*)d_in[12];
    const float* i1_shift  = (const float*)d_in[13];
    const float* i2_w      = (const float*)d_in[14];
    const float* i2_scale  = (const float*)d_in[15];
    const float* i2_shift  = (const float*)d_in[16];
    const float* out_w     = (const float*)d_in[17];
    const float* out_b     = (const float*)d_in[18];

    float* ws   = (float*)d_ws;
    float* A    = ws;                 // 49152
    float* Gc   = ws + 49152;         // 64
    float* Bc   = ws + 49216;         // 64
    float* extT = ws + 49280;         // 5184
    float* wT   = ws + 54464;         // 49152
    float* fn   = ws + 103616;        // 128*196*64 = 1,605,632
    float* bufA = ws + 1709248;       // 80*64*8*196 = 6,422,528 (y0, then y2)
    float* y3   = ws + 8131776;       // 1,605,632
    float* outf = (float*)d_out;      // also scratch for y1 and i2 partials

    k_prep<<<192, 256, 0, stream>>>(in_w, ln_gamma, ext_w, out_w, A, extT, wT);
    k_gb<<<64, 256, 0, stream>>>(in_w, ln_gamma, ln_beta, in_b, Gc, Bc);
    k_lnproj<<<dim3(196, 2), 128, 0, stream>>>(x, A, Gc, Bc, fn);
    k_corr_ext<<<dim3(14, 640), 256, 62368, stream>>>(fn, extT, ext_scale, ext_shift, bufA);
    // i0: bufA -> d_out (y1)
    k_conv3x3<<<dim3(8, 80, 1), 256, 73728, stream>>>(bufA, i0_w, i0_scale, i0_shift, outf, 1, 1);
    // i1: d_out -> bufA (y2)
    k_conv3x3<<<dim3(8, 80, 1), 256, 73728, stream>>>(outf, i1_w, i1_scale, i1_shift, bufA, 1, 1);
    // i2 partials: bufA -> d_out (5 x 16 x 64 x 8 x 196)
    k_conv3x3<<<dim3(8, 16, 5), 256, 73728, stream>>>(bufA, i2_w, nullptr, nullptr, outf, 5, 0);
    k_sum_bn<<<6272, 256, 0, stream>>>(outf, i2_scale, i2_shift, y3);
    k_out<<<dim3(196, 16), 192, 0, stream>>>(y3, wT, out_b, outf);
}

// Round 3
// 906.733 us; speedup vs baseline: 1.3453x; 1.0206x over previous
//
#include <hip/hip_runtime.h>

// Problem constants
// H=W=14, L=196, B=16, T=8, BT=128, D=768, DH=64, Lw=5, U=9, m=4, C=64

__device__ __forceinline__ float gelu_exact(float x) {
    return 0.5f * x * (1.0f + erff(x * 0.70710678118654752440f));
}

// DPP lane-group reduction steps (VALU, not LDS): quad xor1, xor2, then
// half-row mirror (valid because after the first two steps all quad lanes
// hold the quad sum, so 7-i delivers the other quad's sum).
#define DPP_ADD(v, CTRL) \
    ((v) + __int_as_float(__builtin_amdgcn_mov_dpp(__float_as_int(v), (CTRL), 0xF, 0xF, true)))

// ---------------------------------------------------------------------------
// K0a: fold LN gamma into in_w (A = gamma*w), transpose ext_w and out_w
// ---------------------------------------------------------------------------
__global__ void k_prep(const float* __restrict__ in_w, const float* __restrict__ gamma,
                       const float* __restrict__ ext_w, const float* __restrict__ out_w,
                       float* __restrict__ A, float* __restrict__ extT, float* __restrict__ wT) {
    int idx = blockIdx.x * 256 + threadIdx.x;
    if (idx < 64 * 768) {
        int c = idx / 768, d = idx % 768;
        A[idx]  = in_w[idx] * gamma[d];
        wT[idx] = out_w[d * 64 + c];           // wT[c][d] = out_w[d][c]
    }
    if (idx < 81 * 64) {
        int k = idx / 64, co = idx % 64;
        extT[idx] = ext_w[co * 81 + k];        // extT[k][co]
    }
}

// ---------------------------------------------------------------------------
// K0b: Gc[c] = sum_d gamma_d * w[c][d];  Bc[c] = sum_d beta_d * w[c][d] + in_b[c]
// ---------------------------------------------------------------------------
__global__ void k_gb(const float* __restrict__ in_w, const float* __restrict__ gamma,
                     const float* __restrict__ beta, const float* __restrict__ in_b,
                     float* __restrict__ Gc, float* __restrict__ Bc) {
    int c = blockIdx.x, tid = threadIdx.x;
    float s1 = 0.f, s2 = 0.f;
    for (int d = tid; d < 768; d += 256) {
        float w = in_w[c * 768 + d];
        s1 += w * gamma[d];
        s2 += w * beta[d];
    }
    __shared__ float r1[256], r2[256];
    r1[tid] = s1; r2[tid] = s2;
    __syncthreads();
    for (int s = 128; s > 0; s >>= 1) {
        if (tid < s) { r1[tid] += r1[tid + s]; r2[tid] += r2[tid + s]; }
        __syncthreads();
    }
    if (tid == 0) { Gc[c] = r1[0]; Bc[c] = r2[0] + in_b[c]; }
}

// ---------------------------------------------------------------------------
// K1 v2: LayerNorm + projection + channel L2-normalize.
// ---------------------------------------------------------------------------
#define XPITCH(r) ((r) * 68 + ((r) >> 2) * 4)

__global__ __launch_bounds__(128) void k_lnproj(
    const float* __restrict__ x, const float* __restrict__ A,
    const float* __restrict__ Gc, const float* __restrict__ Bc,
    float* __restrict__ fn)
{
    const int l   = blockIdx.x;   // 0..195
    const int bq  = blockIdx.y;   // 0..1
    const int tid = threadIdx.x;  // 0..127

    __shared__ __align__(16) float xs[4416];
    __shared__ __align__(16) float as[4416];
    __shared__ float redA[64][16];
    __shared__ float redB[64][16];
    __shared__ float mu_s[64], rs_s[64], inv_s[64];

    const int btg  = tid >> 3;    // 0..15
    const int cgrp = tid & 7;     // 0..7
    const int b0 = btg * 4, c0 = cgrp * 8;
    const int srow = tid >> 4;    // 0..7
    const int sdq  = tid & 15;    // 0..15

    float acc[4][8] = {};
    float ssum[8] = {}, ssq[8] = {};

#pragma unroll 1
    for (int kc = 0; kc < 12; ++kc) {
#pragma unroll
        for (int k = 0; k < 8; ++k) {
            int r = srow + 8 * k;
            float4 v = *(const float4*)&x[((size_t)(l * 128 + bq * 64 + r)) * 768 + kc * 64 + sdq * 4];
            *(float4*)&xs[XPITCH(r) + sdq * 4] = v;
            ssum[k] += v.x + v.y + v.z + v.w;
            ssq[k]  += v.x * v.x + v.y * v.y + v.z * v.z + v.w * v.w;
        }
#pragma unroll
        for (int k = 0; k < 8; ++k) {
            int c = srow + 8 * k;
            float4 v = *(const float4*)&A[(size_t)c * 768 + kc * 64 + sdq * 4];
            *(float4*)&as[XPITCH(c) + sdq * 4] = v;
        }
        __syncthreads();
#pragma unroll 4
        for (int dq = 0; dq < 16; ++dq) {
            float4 xv[4], av[8];
#pragma unroll
            for (int i = 0; i < 4; ++i)
                xv[i] = *(const float4*)&xs[XPITCH(b0 + i) + dq * 4];
#pragma unroll
            for (int j = 0; j < 8; ++j)
                av[j] = *(const float4*)&as[XPITCH(c0 + j) + dq * 4];
#pragma unroll
            for (int i = 0; i < 4; ++i)
#pragma unroll
                for (int j = 0; j < 8; ++j)
                    acc[i][j] += xv[i].x * av[j].x + xv[i].y * av[j].y +
                                 xv[i].z * av[j].z + xv[i].w * av[j].w;
        }
        __syncthreads();
    }

#pragma unroll
    for (int k = 0; k < 8; ++k) {
        redA[srow + 8 * k][sdq] = ssum[k];
        redB[srow + 8 * k][sdq] = ssq[k];
    }
    __syncthreads();
    if (tid < 64) {
        float s1 = 0.f, s2 = 0.f;
        for (int q = 0; q < 16; ++q) { s1 += redA[tid][q]; s2 += redB[tid][q]; }
        float mu  = s1 * (1.f / 768.f);
        float var = s2 * (1.f / 768.f) - mu * mu;
        mu_s[tid] = mu;
        rs_s[tid] = rsqrtf(var + 1e-5f);
    }
    __syncthreads();

    float h0v[4][8];
#pragma unroll
    for (int i = 0; i < 4; ++i) {
        float mu = mu_s[b0 + i], rs = rs_s[b0 + i];
        float ns = 0.f;
#pragma unroll
        for (int j = 0; j < 8; ++j) {
            float a = rs * acc[i][j] - mu * rs * Gc[c0 + j] + Bc[c0 + j];
            h0v[i][j] = a;
            ns += a * a;
        }
        redA[b0 + i][cgrp] = ns;
    }
    __syncthreads();
    if (tid < 64) {
        float s = 0.f;
        for (int q = 0; q < 8; ++q) s += redA[tid][q];
        inv_s[tid] = 1.f / fmaxf(sqrtf(s), 1e-7f);
    }
    __syncthreads();
#pragma unroll
    for (int i = 0; i < 4; ++i) {
        float inv = inv_s[b0 + i];
        int bt = bq * 64 + b0 + i;
        float4 v0 = make_float4(h0v[i][0] * inv, h0v[i][1] * inv, h0v[i][2] * inv, h0v[i][3] * inv);
        float4 v1 = make_float4(h0v[i][4] * inv, h0v[i][5] * inv, h0v[i][6] * inv, h0v[i][7] * inv);
        *(float4*)&fn[((size_t)bt * 196 + l) * 64 + c0] = v0;
        *(float4*)&fn[((size_t)bt * 196 + l) * 64 + c0 + 4] = v1;
    }
}

// ---------------------------------------------------------------------------
// K2 v3: local correlation (9x9x5) fused with ext 1x1 conv + bn + gelu.
//   grid (14, 640) block 256, static LDS 35.2 KB -> 4 blocks/CU.
//   Phase 1: thread = (du[9] x wgrp[3], ch[8 c-chunks of 4]), c staged in two
//   32-c passes. Per c-quad: 5 src + 13 tgt ds_read_b128 -> 180 FMA
//   (conflict-free: pitch 36 floats, ch contiguous across lanes).
//   c-reduction over the 8 ch lanes via DPP (VALU). Phase 2: float4 csum.
// ---------------------------------------------------------------------------
__global__ __launch_bounds__(256, 4) void k_corr_ext(
    const float* __restrict__ fn, const float* __restrict__ extT,
    const float* __restrict__ e_scale, const float* __restrict__ e_shift,
    float* __restrict__ y0)
{
    __shared__ __align__(16) float smem[8808];
    float* srcT = smem;          // [14][36]
    float* tgtT = smem + 504;    // [9][22][36]
    float* csum = smem + 7632;   // [14][84]

    const int h   = blockIdx.x;
    const int n   = blockIdx.y;
    const int l   = n % 5, t = (n / 5) % 8, b = n / 40;
    const int tid = threadIdx.x;
    const int bt  = b * 8 + t;
    const int tt  = t + l - 2;
    const bool tval = (tt >= 0) && (tt < 8);
    const int bt2 = b * 8 + (tval ? tt : 0);

    const int item = tid >> 3;        // 0..31 (27 used)
    const int ch   = tid & 7;         // c-chunk (4 floats)
    const int du   = item % 9;
    const int wg   = item / 9;        // 0..2
    const int w0   = wg * 5;          // 0,5,10
    const int row  = h + du - 4;
    const bool rvalid = tval && (row >= 0) && (row < 14) && (item < 27);

    float acc[5][9] = {};

#pragma unroll 1
    for (int s = 0; s < 2; ++s) {
        const int cb = s * 32;
        // stage src row h (32 c)
        if (tid < 112) {
            int w = tid >> 3, c4 = tid & 7;
            *(float4*)&srcT[w * 36 + c4 * 4] =
                *(const float4*)&fn[((size_t)bt * 196 + h * 14 + w) * 64 + cb + c4 * 4];
        }
        // stage tgt rows h-4..h+4, width padded to 22 (32 c)
        for (int i4 = tid; i4 < 9 * 22 * 8; i4 += 256) {
            int c4 = i4 & 7, rest = i4 >> 3;
            int xx = rest % 22, r = rest / 22;
            int grow = h + r - 4, xc = xx - 4;
            float4 v = make_float4(0.f, 0.f, 0.f, 0.f);
            if (tval && grow >= 0 && grow < 14 && xc >= 0 && xc < 14)
                v = *(const float4*)&fn[((size_t)bt2 * 196 + grow * 14 + xc) * 64 + cb + c4 * 4];
            *(float4*)&tgtT[rest * 36 + c4 * 4] = v;
        }
        __syncthreads();

        if (rvalid) {
            const float* tp = &tgtT[(du * 22) * 36 + ch * 4];
            float4 sv[5];
#pragma unroll
            for (int wi = 0; wi < 5; ++wi) {
                int w = w0 + wi;
                sv[wi] = (w < 14) ? *(const float4*)&srcT[w * 36 + ch * 4]
                                  : make_float4(0.f, 0.f, 0.f, 0.f);
            }
#pragma unroll
            for (int xi = 0; xi < 13; ++xi) {
                float4 t4 = *(const float4*)&tp[(w0 + xi) * 36];
#pragma unroll
                for (int wi = 0; wi < 5; ++wi) {
                    int dv = xi - wi;
                    if (dv >= 0 && dv < 9)
                        acc[wi][dv] += sv[wi].x * t4.x + sv[wi].y * t4.y +
                                       sv[wi].z * t4.z + sv[wi].w * t4.w;
                }
            }
        }
        __syncthreads();
    }

    // reduce over the 8 ch lanes (DPP, pure VALU)
#pragma unroll
    for (int wi = 0; wi < 5; ++wi)
#pragma unroll
        for (int dv = 0; dv < 9; ++dv) {
            float v = acc[wi][dv];
            v = DPP_ADD(v, 0xB1);   // quad_perm xor1
            v = DPP_ADD(v, 0x4E);   // quad_perm xor2
            v = DPP_ADD(v, 0x141);  // row_half_mirror (cross-quad within 8)
            acc[wi][dv] = v;
        }
    if (ch == 0 && item < 27) {
#pragma unroll
        for (int wi = 0; wi < 5; ++wi) {
            int w = w0 + wi;
            if (w < 14) {
#pragma unroll
                for (int dv = 0; dv < 9; ++dv)
                    csum[w * 84 + du * 9 + dv] = acc[wi][dv];
            }
        }
    }
    __syncthreads();

    // phase 2: ext 1x1 conv (81 -> 64) + bn + gelu, 4 co per thread
    if (tid < 224) {
        const int w = tid % 14, cg = tid / 14;
        const int co0 = cg * 4;
        const float* cp = &csum[w * 84];
        float a0 = 0.f, a1 = 0.f, a2 = 0.f, a3 = 0.f;
#pragma unroll 4
        for (int j = 0; j < 20; ++j) {
            float4 cs = *(const float4*)&cp[j * 4];
            float4 e0 = *(const float4*)&extT[(j * 4 + 0) * 64 + co0];
            float4 e1 = *(const float4*)&extT[(j * 4 + 1) * 64 + co0];
            float4 e2 = *(const float4*)&extT[(j * 4 + 2) * 64 + co0];
            float4 e3 = *(const float4*)&extT[(j * 4 + 3) * 64 + co0];
            a0 = fmaf(cs.x, e0.x, a0); a1 = fmaf(cs.x, e0.y, a1);
            a2 = fmaf(cs.x, e0.z, a2); a3 = fmaf(cs.x, e0.w, a3);
            a0 = fmaf(cs.y, e1.x, a0); a1 = fmaf(cs.y, e1.y, a1);
            a2 = fmaf(cs.y, e1.z, a2); a3 = fmaf(cs.y, e1.w, a3);
            a0 = fmaf(cs.z, e2.x, a0); a1 = fmaf(cs.z, e2.y, a1);
            a2 = fmaf(cs.z, e2.z, a2); a3 = fmaf(cs.z, e2.w, a3);
            a0 = fmaf(cs.w, e3.x, a0); a1 = fmaf(cs.w, e3.y, a1);
            a2 = fmaf(cs.w, e3.z, a2); a3 = fmaf(cs.w, e3.w, a3);
        }
        float c80 = cp[80];
        float4 e = *(const float4*)&extT[80 * 64 + co0];
        a0 = fmaf(c80, e.x, a0); a1 = fmaf(c80, e.y, a1);
        a2 = fmaf(c80, e.z, a2); a3 = fmaf(c80, e.w, a3);

        const size_t obase = ((size_t)(b * 5 + l) * 64) * 1568 + (size_t)t * 196 + h * 14;
        float r[4] = {a0, a1, a2, a3};
#pragma unroll
        for (int j = 0; j < 4; ++j) {
            float v = gelu_exact(r[j] * e_scale[co0 + j] + e_shift[co0 + j]);
            y0[obase + (size_t)(co0 + j) * 1568 + w] = v;
        }
    }
}

// ---------------------------------------------------------------------------
// 3x3 spatial conv (depth kernel 1, pad 1 on H,W), 64 c_in chunk -> 64 c_out.
//   grid (8, NB, NZ) block 256, dynamic LDS 73728 B.
// ---------------------------------------------------------------------------
__global__ __launch_bounds__(256) void k_conv3x3(
    const float* __restrict__ in, const float* __restrict__ w,
    const float* __restrict__ scale, const float* __restrict__ shift,
    float* __restrict__ out, int CT, int bn)
{
    extern __shared__ float smem[];
    float* inp = smem;   // [64][16*18]

    const int t   = blockIdx.x;
    const int nb  = blockIdx.y;
    const int z   = blockIdx.z;
    const int tid = threadIdx.x;
    const int CIN9 = CT * 64 * 9;

    for (int i = tid; i < (64 * 288) / 2; i += 256)
        ((float2*)inp)[i] = make_float2(0.f, 0.f);
    __syncthreads();
    const size_t ibase = ((size_t)(nb * CT + z) * 64) * 1568 + (size_t)t * 196;
    for (int i = tid; i < 64 * 196; i += 256) {
        int ci = i / 196, pos = i % 196;
        int hh = pos / 14, ww = pos % 14;
        inp[ci * 288 + (hh + 1) * 18 + (ww + 1)] = in[ibase + (size_t)ci * 1568 + pos];
    }
    __syncthreads();

    float acc[4][14] = {};
    const int cg = tid / 14, hr = tid % 14;
    const int co0 = cg * 4;
    if (tid < 224) {
        for (int ci = 0; ci < 64; ++ci) {
            float r[3][16];
#pragma unroll
            for (int kh = 0; kh < 3; ++kh)
#pragma unroll
                for (int k2 = 0; k2 < 8; ++k2)
                    *(float2*)&r[kh][k2 * 2] =
                        *(const float2*)&inp[ci * 288 + (hr + kh) * 18 + k2 * 2];
            const float* wp = &w[(size_t)(z * 64 + ci) * 9];
#pragma unroll
            for (int kh = 0; kh < 3; ++kh)
#pragma unroll
                for (int kw = 0; kw < 3; ++kw) {
                    float wv[4];
#pragma unroll
                    for (int j = 0; j < 4; ++j)
                        wv[j] = wp[(size_t)(co0 + j) * CIN9 + kh * 3 + kw];
#pragma unroll
                    for (int j = 0; j < 4; ++j)
#pragma unroll
                        for (int q = 0; q < 14; ++q)
                            acc[j][q] = fmaf(r[kh][q + kw], wv[j], acc[j][q]);
                }
        }
        if (bn) {
#pragma unroll
            for (int j = 0; j < 4; ++j) {
                int co = co0 + j;
                float sc = scale[co], sh = shift[co];
                size_t ob = (size_t)(nb * 64 + co) * 1568 + (size_t)t * 196 + hr * 14;
#pragma unroll
                for (int q = 0; q < 14; ++q)
                    out[ob + q] = gelu_exact(acc[j][q] * sc + sh);
            }
        } else {
#pragma unroll
            for (int j = 0; j < 4; ++j) {
                int co = co0 + j;
                size_t ob = ((size_t)(z * gridDim.y + nb) * 64 + co) * 1568 + (size_t)t * 196 + hr * 14;
#pragma unroll
                for (int q = 0; q < 14; ++q)
                    out[ob + q] = acc[j][q];
            }
        }
    }
}

// ---------------------------------------------------------------------------
// K_sum: sum the 5 i2 partials + bn + gelu -> y3 (16,64,8,196)
// ---------------------------------------------------------------------------
__global__ void k_sum_bn(const float* __restrict__ yp, const float* __restrict__ scale,
                         const float* __restrict__ shift, float* __restrict__ y3) {
    int idx = blockIdx.x * 256 + threadIdx.x;
    if (idx >= 16 * 64 * 8 * 196) return;
    float s = 0.f;
#pragma unroll
    for (int z = 0; z < 5; ++z) s += yp[(size_t)z * 1605632 + idx];
    int co = (idx / 1568) & 63;
    y3[idx] = gelu_exact(s * scale[co] + shift[co]);
}

// ---------------------------------------------------------------------------
// K6: output GEMM  out[l][bt][d] = sum_c y3[b][c][t][l] * wT[c][d] + out_b[d]
// ---------------------------------------------------------------------------
__global__ __launch_bounds__(192) void k_out(
    const float* __restrict__ y3, const float* __restrict__ wT,
    const float* __restrict__ out_b, float* __restrict__ out)
{
    const int l   = blockIdx.x;
    const int bg  = blockIdx.y;
    const int tid = threadIdx.x;
    __shared__ __align__(16) float ysB[8][64];
    for (int i = tid; i < 512; i += 192) {
        int bl = i >> 6, c = i & 63;
        int bt = bg * 8 + bl;
        ysB[bl][c] = y3[((size_t)((bt >> 3) * 64 + c) * 8 + (bt & 7)) * 196 + l];
    }
    __syncthreads();
    const int d0 = tid * 4;
    float acc[8][4] = {};
    for (int cq = 0; cq < 16; ++cq) {
        float4 ys[8];
#pragma unroll
        for (int i = 0; i < 8; ++i) ys[i] = *(const float4*)&ysB[i][cq * 4];
#pragma unroll
        for (int cc = 0; cc < 4; ++cc) {
            float4 wv = *(const float4*)&wT[(size_t)(cq * 4 + cc) * 768 + d0];
#pragma unroll
            for (int i = 0; i < 8; ++i) {
                float yv = (cc == 0) ? ys[i].x : (cc == 1) ? ys[i].y : (cc == 2) ? ys[i].z : ys[i].w;
                acc[i][0] = fmaf(yv, wv.x, acc[i][0]);
                acc[i][1] = fmaf(yv, wv.y, acc[i][1]);
                acc[i][2] = fmaf(yv, wv.z, acc[i][2]);
                acc[i][3] = fmaf(yv, wv.w, acc[i][3]);
            }
        }
    }
    float4 ob = *(const float4*)&out_b[d0];
#pragma unroll
    for (int i = 0; i < 8; ++i) {
        float4 v = make_float4(acc[i][0] + ob.x, acc[i][1] + ob.y,
                               acc[i][2] + ob.z, acc[i][3] + ob.w);
        *(float4*)&out[((size_t)(l * 128 + bg * 8 + i)) * 768 + d0] = v;
    }
}

// ---------------------------------------------------------------------------
extern "C" void kernel_launch(void* const* d_in, const int* in_sizes, int n_in,
                              void* d_out, int out_size, void* d_ws, size_t ws_size,
                              hipStream_t stream) {
    const float* x         = (const float*)d_in[0];
    const float* ln_gamma  = (const float*)d_in[1];
    const float* ln_beta   = (const float*)d_in[2];
    const float* in_w      = (const float*)d_in[3];
    const float* in_b      = (const float*)d_in[4];
    const float* ext_w     = (const float*)d_in[5];
    const float* ext_scale = (const float*)d_in[6];
    const float* ext_shift = (const float*)d_in[7];
    const float* i0_w      = (const float*)d_in[8];
    const float* i0_scale  = (const float*)d_in[9];
    const float* i0_shift  = (const float*)d_in[10];
    const float* i1_w      = (const float*)d_in[11];
    const float* i1_scale  = (const float*)d_in[12];
    const float* i1_shift  = (const float*)d_in[13];
    const float* i2_w      = (const float*)d_in[14];
    const float* i2_scale  = (const float*)d_in[15];
    const float* i2_shift  = (const float*)d_in[16];
    const float* out_w     = (const float*)d_in[17];
    const float* out_b     = (const float*)d_in[18];

    float* ws   = (float*)d_ws;
    float* A    = ws;                 // 49152
    float* Gc   = ws + 49152;         // 64
    float* Bc   = ws + 49216;         // 64
    float* extT = ws + 49280;         // 5184
    float* wT   = ws + 54464;         // 49152
    float* fn   = ws + 103616;        // 128*196*64 = 1,605,632
    float* bufA = ws + 1709248;       // 80*64*8*196 = 6,422,528 (y0, then y2)
    float* y3   = ws + 8131776;       // 1,605,632
    float* outf = (float*)d_out;      // also scratch for y1 and i2 partials

    k_prep<<<192, 256, 0, stream>>>(in_w, ln_gamma, ext_w, out_w, A, extT, wT);
    k_gb<<<64, 256, 0, stream>>>(in_w, ln_gamma, ln_beta, in_b, Gc, Bc);
    k_lnproj<<<dim3(196, 2), 128, 0, stream>>>(x, A, Gc, Bc, fn);
    k_corr_ext<<<dim3(14, 640), 256, 0, stream>>>(fn, extT, ext_scale, ext_shift, bufA);
    // i0: bufA -> d_out (y1)
    k_conv3x3<<<dim3(8, 80, 1), 256, 73728, stream>>>(bufA, i0_w, i0_scale, i0_shift, outf, 1, 1);
    // i1: d_out -> bufA (y2)
    k_conv3x3<<<dim3(8, 80, 1), 256, 73728, stream>>>(outf, i1_w, i1_scale, i1_shift, bufA, 1, 1);
    // i2 partials: bufA -> d_out (5 x 16 x 64 x 8 x 196)
    k_conv3x3<<<dim3(8, 16, 5), 256, 73728, stream>>>(bufA, i2_w, nullptr, nullptr, outf, 5, 0);
    k_sum_bn<<<6272, 256, 0, stream>>>(outf, i2_scale, i2_shift, y3);
    k_out<<<dim3(196, 16), 192, 0, stream>>>(y3, wT, out_b, outf);
}